// Round 1
// baseline (162.092 us; speedup 1.0000x reference)
//
#include <hip/hip_runtime.h>
#include <math.h>

#define NN 2048
#define EE 1024
#define DD 64

typedef unsigned long long ull;

__device__ __forceinline__ float wave_reduce_sum(float v) {
  #pragma unroll
  for (int o = 32; o > 0; o >>= 1) v += __shfl_xor(v, o, 64);
  return v;
}

// deg_n -> dn = deg>0 ? deg^-1/2 : 0.  one wave per node row of H [NN][EE]
__global__ void k_dn(const float* __restrict__ H, float* __restrict__ dn) {
  int wid = (blockIdx.x * blockDim.x + threadIdx.x) >> 6;
  int lane = threadIdx.x & 63;
  const float* row = H + (size_t)wid * EE;
  float s = 0.f;
  #pragma unroll
  for (int i = 0; i < EE; i += 64) s += row[i + lane];
  s = wave_reduce_sum(s);
  if (lane == 0) dn[wid] = s > 0.f ? rsqrtf(s) : 0.f;
}

// HT[e][n] = H[n][e]
__global__ void k_tr(const float* __restrict__ H, float* __restrict__ HT) {
  __shared__ float tile[64][65];
  int t = threadIdx.x;
  int tx = t & 63, ty = t >> 6;  // ty in 0..3
  int bx = blockIdx.x;           // e tile (EE/64)
  int by = blockIdx.y;           // n tile (NN/64)
  #pragma unroll
  for (int i = 0; i < 64; i += 4)
    tile[ty + i][tx] = H[(size_t)(by * 64 + ty + i) * EE + bx * 64 + tx];
  __syncthreads();
  #pragma unroll
  for (int i = 0; i < 64; i += 4)
    HT[(size_t)(bx * 64 + ty + i) * NN + by * 64 + tx] = tile[tx][ty + i];
}

// deg_e -> de = deg>0 ? 1/deg : 0.  one wave per edge row of HT [EE][NN]
__global__ void k_de(const float* __restrict__ HT, float* __restrict__ de) {
  int wid = (blockIdx.x * blockDim.x + threadIdx.x) >> 6;
  int lane = threadIdx.x & 63;
  const float* row = HT + (size_t)wid * NN;
  float s = 0.f;
  #pragma unroll
  for (int i = 0; i < NN; i += 64) s += row[i + lane];
  s = wave_reduce_sum(s);
  if (lane == 0) de[wid] = s > 0.f ? 1.f / s : 0.f;
}

// out[r][h] = (addb ? b1[h] : 0) + sum_d in[r][d] * W1[h][woff+d]
// block: 256 threads = 2 rows x 128 h.  W1 half staged in LDS (padded).
__global__ void k_lin(const float* __restrict__ in, const float* __restrict__ W1,
                      const float* __restrict__ b1, float* __restrict__ out,
                      int woff, int addb) {
  __shared__ float Wl[128 * 65];
  __shared__ float xl[2][64];
  int t = threadIdx.x;
  for (int j = t; j < 128 * 64; j += 256) {
    int h = j >> 6, d = j & 63;
    Wl[h * 65 + d] = W1[h * 128 + woff + d];
  }
  int r0 = blockIdx.x * 2;
  if (t < 128) xl[t >> 6][t & 63] = in[(size_t)(r0 + (t >> 6)) * 64 + (t & 63)];
  __syncthreads();
  int rl = t >> 7;     // 0..1
  int h = t & 127;
  float acc = addb ? b1[h] : 0.f;
  #pragma unroll
  for (int d = 0; d < 64; ++d)
    acc += xl[rl][d] * Wl[h * 65 + d];
  out[(size_t)(r0 + rl) * 128 + h] = acc;
}

// ef[e][d] = sum_{n: H[n][e]!=0} x[n][d].  wave per edge, lane = d.
__global__ void k_ef(const float* __restrict__ HT, const float* __restrict__ x,
                     float* __restrict__ ef) {
  int e = (blockIdx.x * blockDim.x + threadIdx.x) >> 6;
  int lane = threadIdx.x & 63;
  const float* row = HT + (size_t)e * NN;
  float acc = 0.f;
  for (int i = 0; i < NN; i += 64) {
    float hv = row[i + lane];
    ull m = __ballot(hv != 0.f);
    while (m) {
      int b = __ffsll(m) - 1;
      m &= m - 1;
      acc += x[(size_t)(i + b) * 64 + lane];
    }
  }
  ef[(size_t)e * 64 + lane] = acc;
}

// scores at nnz only: sT[e][n] = sigmoid( sum_h relu(np[n][h]+ep[e][h]) * W2[h] + b2 )
// (b1 already folded into np).  wave per node; lane covers h=lane and h=lane+64.
__global__ void k_score(const float* __restrict__ H, const float* __restrict__ npb,
                        const float* __restrict__ epb, const float* __restrict__ W2,
                        const float* __restrict__ b2, float* __restrict__ sT) {
  int n = (blockIdx.x * blockDim.x + threadIdx.x) >> 6;
  int lane = threadIdx.x & 63;
  float npa = npb[(size_t)n * 128 + lane];
  float npc = npb[(size_t)n * 128 + 64 + lane];
  float w2a = W2[lane], w2b = W2[64 + lane];
  float b2v = b2[0];
  const float* row = H + (size_t)n * EE;
  for (int i = 0; i < EE; i += 64) {
    float hv = row[i + lane];
    ull m = __ballot(hv != 0.f);
    while (m) {
      int b = __ffsll(m) - 1;
      m &= m - 1;
      int e = i + b;
      float tv = fmaxf(npa + epb[(size_t)e * 128 + lane], 0.f) * w2a
               + fmaxf(npc + epb[(size_t)e * 128 + 64 + lane], 0.f) * w2b;
      tv = wave_reduce_sum(tv);
      if (lane == 0) {
        float sc = tv + b2v;
        sT[(size_t)e * NN + n] = 1.f / (1.f + __expf(-sc));
      }
    }
  }
}

// w[e][d] = de[e] * sum_{n in col(e)} sT[e][n] * dn[n] * x[n][d]
__global__ void k_v(const float* __restrict__ HT, const float* __restrict__ sT,
                    const float* __restrict__ dn, const float* __restrict__ de,
                    const float* __restrict__ x, float* __restrict__ w) {
  int e = (blockIdx.x * blockDim.x + threadIdx.x) >> 6;
  int lane = threadIdx.x & 63;
  const float* row = HT + (size_t)e * NN;
  float acc = 0.f;
  for (int i = 0; i < NN; i += 64) {
    float hv = row[i + lane];
    ull m = __ballot(hv != 0.f);
    while (m) {
      int b = __ffsll(m) - 1;
      m &= m - 1;
      int n = i + b;
      float s = sT[(size_t)e * NN + n] * dn[n];
      acc += s * x[(size_t)n * 64 + lane];
    }
  }
  w[(size_t)e * 64 + lane] = de[e] * acc;
}

// y[n][d] = dn[n] * sum_{e in row(n)} sT[e][n] * w[e][d]
__global__ void k_z(const float* __restrict__ H, const float* __restrict__ sT,
                    const float* __restrict__ dn, const float* __restrict__ w,
                    float* __restrict__ y) {
  int n = (blockIdx.x * blockDim.x + threadIdx.x) >> 6;
  int lane = threadIdx.x & 63;
  const float* row = H + (size_t)n * EE;
  float acc = 0.f;
  for (int i = 0; i < EE; i += 64) {
    float hv = row[i + lane];
    ull m = __ballot(hv != 0.f);
    while (m) {
      int b = __ffsll(m) - 1;
      m &= m - 1;
      int e = i + b;
      acc += sT[(size_t)e * NN + n] * w[(size_t)e * 64 + lane];
    }
  }
  y[(size_t)n * 64 + lane] = dn[n] * acc;
}

// out[n][o] = sum_d y[n][d] * Wl[o][d] + bl[o].  block = 4 nodes x 64 o.
__global__ void k_out(const float* __restrict__ y, const float* __restrict__ Wlg,
                      const float* __restrict__ bl, float* __restrict__ out) {
  __shared__ float yl[4][64];
  __shared__ float Wlds[64][65];
  int t = threadIdx.x;
  int n0 = blockIdx.x * 4;
  for (int j = t; j < 4096; j += 256) Wlds[j >> 6][j & 63] = Wlg[j];
  yl[t >> 6][t & 63] = y[(size_t)n0 * 64 + t];
  __syncthreads();
  int rl = t >> 6, o = t & 63;
  float acc = bl[o];
  #pragma unroll
  for (int d = 0; d < 64; ++d)
    acc += yl[rl][d] * Wlds[o][d];
  out[(size_t)(n0 + rl) * 64 + o] = acc;
}

extern "C" void kernel_launch(void* const* d_in, const int* in_sizes, int n_in,
                              void* d_out, int out_size, void* d_ws, size_t ws_size,
                              hipStream_t stream) {
  const float* x  = (const float*)d_in[0];
  const float* H  = (const float*)d_in[1];
  const float* W1 = (const float*)d_in[2];
  const float* b1 = (const float*)d_in[3];
  const float* W2 = (const float*)d_in[4];
  const float* b2 = (const float*)d_in[5];
  const float* Wl = (const float*)d_in[6];
  const float* bl = (const float*)d_in[7];
  float* out = (float*)d_out;

  float* ws = (float*)d_ws;
  float* dn  = ws; ws += NN;
  float* de  = ws; ws += EE;
  float* ef  = ws; ws += EE * DD;
  float* npb = ws; ws += NN * 128;
  float* epb = ws; ws += EE * 128;
  float* w   = ws; ws += EE * DD;
  float* y   = ws; ws += NN * DD;
  float* HT  = ws; ws += (size_t)EE * NN;
  float* sT  = ws; ws += (size_t)EE * NN;

  hipLaunchKernelGGL(k_dn, dim3(NN / 4), dim3(256), 0, stream, H, dn);
  hipLaunchKernelGGL(k_tr, dim3(EE / 64, NN / 64), dim3(256), 0, stream, H, HT);
  hipLaunchKernelGGL(k_de, dim3(EE / 4), dim3(256), 0, stream, HT, de);
  hipLaunchKernelGGL(k_lin, dim3(NN / 2), dim3(256), 0, stream, x, W1, b1, npb, 0, 1);
  hipLaunchKernelGGL(k_ef, dim3(EE / 4), dim3(256), 0, stream, HT, x, ef);
  hipLaunchKernelGGL(k_lin, dim3(EE / 2), dim3(256), 0, stream, ef, W1, b1, epb, 64, 0);
  hipLaunchKernelGGL(k_score, dim3(NN / 4), dim3(256), 0, stream, H, npb, epb, W2, b2, sT);
  hipLaunchKernelGGL(k_v, dim3(EE / 4), dim3(256), 0, stream, HT, sT, dn, de, x, w);
  hipLaunchKernelGGL(k_z, dim3(NN / 4), dim3(256), 0, stream, H, sT, dn, w, y);
  hipLaunchKernelGGL(k_out, dim3(NN / 4), dim3(256), 0, stream, y, Wl, bl, out);
}

// Round 2
// 138.996 us; speedup vs baseline: 1.1662x; 1.1662x over previous
//
#include <hip/hip_runtime.h>
#include <math.h>

#define NN 2048
#define EE 1024

__device__ __forceinline__ float wave_reduce_sum(float v) {
  #pragma unroll
  for (int o = 32; o > 0; o >>= 1) v += __shfl_xor(v, o, 64);
  return v;
}

// dn[n] = deg>0 ? deg^-1/2 : 0.  one wave per node row of H [NN][EE]
__global__ void k_dn(const float* __restrict__ H, float* __restrict__ dn) {
  int wid = (blockIdx.x * blockDim.x + threadIdx.x) >> 6;
  int lane = threadIdx.x & 63;
  const float* row = H + (size_t)wid * EE;
  float s = 0.f;
  #pragma unroll
  for (int i = 0; i < EE; i += 64) s += row[i + lane];
  s = wave_reduce_sum(s);
  if (lane == 0) dn[wid] = s > 0.f ? rsqrtf(s) : 0.f;
}

// column-sum partials of H: dpart[by][e] = sum over 256 rows
__global__ void k_colsum_part(const float* __restrict__ H, float* __restrict__ dpart) {
  int e = blockIdx.x * 256 + threadIdx.x;
  int r0 = blockIdx.y * 256;
  float s = 0.f;
  #pragma unroll 8
  for (int n = 0; n < 256; ++n) s += H[(size_t)(r0 + n) * EE + e];
  dpart[blockIdx.y * EE + e] = s;
}

__global__ void k_de_fin(const float* __restrict__ dpart, float* __restrict__ de) {
  int e = blockIdx.x * 256 + threadIdx.x;
  float s = 0.f;
  #pragma unroll
  for (int p = 0; p < 8; ++p) s += dpart[p * EE + e];
  de[e] = s > 0.f ? 1.f / s : 0.f;
}

// out[r][h] = (addb ? b1[h] : 0) + sum_d in[r][d] * W1[h][woff+d]
__global__ void k_lin(const float* __restrict__ in, const float* __restrict__ W1,
                      const float* __restrict__ b1, float* __restrict__ out,
                      int woff, int addb) {
  __shared__ float Wl[128 * 65];
  __shared__ float xl[2][64];
  int t = threadIdx.x;
  for (int j = t; j < 128 * 64; j += 256) {
    int h = j >> 6, d = j & 63;
    Wl[h * 65 + d] = W1[h * 128 + woff + d];
  }
  int r0 = blockIdx.x * 2;
  if (t < 128) xl[t >> 6][t & 63] = in[(size_t)(r0 + (t >> 6)) * 64 + (t & 63)];
  __syncthreads();
  int rl = t >> 7;
  int h = t & 127;
  float acc = addb ? b1[h] : 0.f;
  #pragma unroll
  for (int d = 0; d < 64; ++d)
    acc += xl[rl][d] * Wl[h * 65 + d];
  out[(size_t)(r0 + rl) * 128 + h] = acc;
}

// split-K tiled GEMM: part[kb][m][d] = sum_{k in tile kb} A'[m][k] * sB[k]*B[k][d]
// TRANSA: A' = A^T stored [K][M] (A[k*lda+m]); else A stored [M][K] (A[m*lda+k]).
// B is [K][64].  grid = (Mdim/64, K/64), block 256.
template <bool TRANSA>
__global__ void k_gemm(const float* __restrict__ A, int lda,
                       const float* __restrict__ B, const float* __restrict__ sB,
                       float* __restrict__ part, int Mdim) {
  __shared__ float Al[64 * 68];  // Al[k][m]
  __shared__ float Bl[64 * 68];  // Bl[k][d]
  int t = threadIdx.x;
  int m0 = blockIdx.x * 64, k0 = blockIdx.y * 64;
  #pragma unroll
  for (int p = 0; p < 16; ++p) {
    int idx = t + p * 256;
    int i = idx >> 6, j = idx & 63;
    if (TRANSA) Al[i * 68 + j] = A[(size_t)(k0 + i) * lda + m0 + j];
    else        Al[j * 68 + i] = A[(size_t)(m0 + i) * lda + k0 + j];
  }
  #pragma unroll
  for (int p = 0; p < 16; ++p) {
    int idx = t + p * 256;
    int i = idx >> 6, d = idx & 63;
    float v = B[(size_t)(k0 + i) * 64 + d];
    if (sB) v *= sB[k0 + i];
    Bl[i * 68 + d] = v;
  }
  __syncthreads();
  int me0 = (t & 15) * 4, d0 = (t >> 4) * 4;
  float acc[4][4] = {};
  #pragma unroll 8
  for (int k = 0; k < 64; ++k) {
    float av[4], bv[4];
    *(float4*)av = *(const float4*)&Al[k * 68 + me0];
    *(float4*)bv = *(const float4*)&Bl[k * 68 + d0];
    #pragma unroll
    for (int r = 0; r < 4; ++r)
      #pragma unroll
      for (int c = 0; c < 4; ++c)
        acc[r][c] += av[r] * bv[c];
  }
  float* po = part + (size_t)blockIdx.y * Mdim * 64;
  #pragma unroll
  for (int r = 0; r < 4; ++r)
    *(float4*)&po[(size_t)(m0 + me0 + r) * 64 + d0] = *(float4*)acc[r];
}

// out[m][d] = (smode ? scale[m] : 1) * sum_s part[s][m][d]
__global__ void k_red(const float* __restrict__ part, int S, int Mdim,
                      const float* __restrict__ scale, int smode,
                      float* __restrict__ out) {
  int idx = blockIdx.x * 256 + threadIdx.x;
  float s = 0.f;
  for (int p = 0; p < S; ++p) s += part[(size_t)p * Mdim * 64 + idx];
  if (smode) s *= scale[idx >> 6];
  out[idx] = s;
}

// dense attention scores, masked by H:
// Mmat[n][e] = H[n][e] * sigmoid( sum_h relu(np[n][h]+ep[e][h]) * w2[h] + b2 )
// tile: 32 n x 64 e per block; micro-tile 2n x 4e per thread.
__global__ void k_score(const float* __restrict__ npb, const float* __restrict__ epb,
                        const float* __restrict__ W2, const float* __restrict__ b2,
                        const float* __restrict__ H, float* __restrict__ Mmat) {
  __shared__ float epl[128 * 68];  // [h][e]
  __shared__ float npl[128 * 36];  // [h][n]
  __shared__ float w2l[128];
  int t = threadIdx.x;
  int e0 = blockIdx.x * 64, n0 = blockIdx.y * 32;
  #pragma unroll
  for (int p = 0; p < 32; ++p) {
    int idx = t + p * 256;
    int e = idx >> 7, h = idx & 127;
    epl[h * 68 + e] = epb[(size_t)(e0 + e) * 128 + h];
  }
  #pragma unroll
  for (int p = 0; p < 16; ++p) {
    int idx = t + p * 256;
    int n = idx >> 7, h = idx & 127;
    npl[h * 36 + n] = npb[(size_t)(n0 + n) * 128 + h];
  }
  if (t < 128) w2l[t] = W2[t];
  __syncthreads();
  int ee0 = (t & 15) * 4, nn0 = (t >> 4) * 2;
  float acc[2][4] = {};
  #pragma unroll 8
  for (int h = 0; h < 128; ++h) {
    float w2h = w2l[h];
    float nv[2], ev[4];
    *(float2*)nv = *(const float2*)&npl[h * 36 + nn0];
    *(float4*)ev = *(const float4*)&epl[h * 68 + ee0];
    #pragma unroll
    for (int r = 0; r < 2; ++r)
      #pragma unroll
      for (int c = 0; c < 4; ++c)
        acc[r][c] += fmaxf(nv[r] + ev[c], 0.f) * w2h;
  }
  float b2v = b2[0];
  #pragma unroll
  for (int r = 0; r < 2; ++r) {
    int n = n0 + nn0 + r;
    float hv[4], mo[4];
    *(float4*)hv = *(const float4*)&H[(size_t)n * EE + e0 + ee0];
    #pragma unroll
    for (int c = 0; c < 4; ++c) {
      float sg = 1.f / (1.f + __expf(-(acc[r][c] + b2v)));
      mo[c] = hv[c] * sg;
    }
    *(float4*)&Mmat[(size_t)n * EE + e0 + ee0] = *(float4*)mo;
  }
}

// out[n][o] = sum_d y[n][d] * Wl[o][d] + bl[o]
__global__ void k_out(const float* __restrict__ y, const float* __restrict__ Wlg,
                      const float* __restrict__ bl, float* __restrict__ out) {
  __shared__ float yl[4][64];
  __shared__ float Wlds[64][65];
  int t = threadIdx.x;
  int n0 = blockIdx.x * 4;
  for (int j = t; j < 4096; j += 256) Wlds[j >> 6][j & 63] = Wlg[j];
  yl[t >> 6][t & 63] = y[(size_t)n0 * 64 + t];
  __syncthreads();
  int rl = t >> 6, o = t & 63;
  float acc = bl[o];
  #pragma unroll
  for (int d = 0; d < 64; ++d)
    acc += yl[rl][d] * Wlds[o][d];
  out[(size_t)(n0 + rl) * 64 + o] = acc;
}

extern "C" void kernel_launch(void* const* d_in, const int* in_sizes, int n_in,
                              void* d_out, int out_size, void* d_ws, size_t ws_size,
                              hipStream_t stream) {
  const float* x  = (const float*)d_in[0];
  const float* H  = (const float*)d_in[1];
  const float* W1 = (const float*)d_in[2];
  const float* b1 = (const float*)d_in[3];
  const float* W2 = (const float*)d_in[4];
  const float* b2 = (const float*)d_in[5];
  const float* Wl = (const float*)d_in[6];
  const float* bl = (const float*)d_in[7];
  float* out = (float*)d_out;

  float* ws = (float*)d_ws;
  float* dn    = ws; ws += NN;
  float* de    = ws; ws += EE;
  float* dpart = ws; ws += 8 * EE;
  float* npb   = ws; ws += NN * 128;
  float* epb   = ws; ws += EE * 128;
  float* ef    = ws; ws += EE * 64;
  float* w     = ws; ws += EE * 64;
  float* y     = ws; ws += NN * 64;
  float* Mmat  = ws; ws += (size_t)NN * EE;
  float* part  = ws; ws += (size_t)NN * EE;  // reused by all 3 GEMMs

  // degrees / scalings
  hipLaunchKernelGGL(k_dn, dim3(NN / 4), dim3(256), 0, stream, H, dn);
  hipLaunchKernelGGL(k_colsum_part, dim3(EE / 256, 8), dim3(256), 0, stream, H, dpart);
  hipLaunchKernelGGL(k_de_fin, dim3(EE / 256), dim3(256), 0, stream, dpart, de);
  // node projection
  hipLaunchKernelGGL(k_lin, dim3(NN / 2), dim3(256), 0, stream, x, W1, b1, npb, 0, 1);
  // ef = H^T @ x
  hipLaunchKernelGGL(k_gemm<true>, dim3(EE / 64, NN / 64), dim3(256), 0, stream,
                     H, EE, x, (const float*)nullptr, part, EE);
  hipLaunchKernelGGL(k_red, dim3(EE * 64 / 256), dim3(256), 0, stream,
                     part, NN / 64, EE, (const float*)nullptr, 0, ef);
  // edge projection
  hipLaunchKernelGGL(k_lin, dim3(EE / 2), dim3(256), 0, stream, ef, W1, b1, epb, 64, 0);
  // masked attention matrix
  hipLaunchKernelGGL(k_score, dim3(EE / 64, NN / 32), dim3(256), 0, stream,
                     npb, epb, W2, b2, H, Mmat);
  // t = M^T @ (dn*x);  w = de * t
  hipLaunchKernelGGL(k_gemm<true>, dim3(EE / 64, NN / 64), dim3(256), 0, stream,
                     Mmat, EE, x, dn, part, EE);
  hipLaunchKernelGGL(k_red, dim3(EE * 64 / 256), dim3(256), 0, stream,
                     part, NN / 64, EE, de, 1, w);
  // z = M @ w;  y = dn * z
  hipLaunchKernelGGL(k_gemm<false>, dim3(NN / 64, EE / 64), dim3(256), 0, stream,
                     Mmat, EE, w, (const float*)nullptr, part, NN);
  hipLaunchKernelGGL(k_red, dim3(NN * 64 / 256), dim3(256), 0, stream,
                     part, EE / 64, NN, dn, 1, y);
  // final linear
  hipLaunchKernelGGL(k_out, dim3(NN / 4), dim3(256), 0, stream, y, Wl, bl, out);
}